// Round 1
// baseline (1611.714 us; speedup 1.0000x reference)
//
#include <hip/hip_runtime.h>
#include <cstdint>

#define NNODES 10000
#define NEDGES 160000
#define TOT_E  (NEDGES + NNODES)
#define HEADS  8

// ---------------- CSR build (dst-sorted) ----------------
__global__ void count_k(const int* __restrict__ ei, int* __restrict__ deg) {
    int i = blockIdx.x * 256 + threadIdx.x;
    if (i >= TOT_E) return;
    int dst = (i < NEDGES) ? ei[NEDGES + i] : (i - NEDGES);   // self-loop: dst = node
    atomicAdd(deg + dst, 1);
}

__global__ void scan_k(const int* __restrict__ deg, int* __restrict__ rows) {
    __shared__ int buf[256];
    __shared__ int carry;
    if (threadIdx.x == 0) carry = 0;
    __syncthreads();
    for (int base = 0; base < NNODES; base += 256) {
        int i = base + threadIdx.x;
        int v = (i < NNODES) ? deg[i] : 0;
        buf[threadIdx.x] = v;
        __syncthreads();
        for (int off = 1; off < 256; off <<= 1) {
            int t = (threadIdx.x >= off) ? buf[threadIdx.x - off] : 0;
            __syncthreads();
            buf[threadIdx.x] += t;
            __syncthreads();
        }
        if (i < NNODES) rows[i + 1] = carry + buf[threadIdx.x];
        __syncthreads();
        if (threadIdx.x == 255) carry += buf[255];
        __syncthreads();
    }
    if (threadIdx.x == 0) rows[0] = 0;
}

__global__ void scatter_k(const int* __restrict__ ei, const int* __restrict__ rows,
                          int* __restrict__ cursor, int* __restrict__ esrc) {
    int i = blockIdx.x * 256 + threadIdx.x;
    if (i >= TOT_E) return;
    int src, dst;
    if (i < NEDGES) { src = ei[i]; dst = ei[NEDGES + i]; }
    else            { src = i - NEDGES; dst = src; }
    int pos = atomicAdd(cursor + dst, 1);
    esrc[rows[dst] + pos] = src;
}

// ---------------- fp32 GEMM: C[M,Ncols] = A[M,K] * W[Ncols,K]^T ----------------
// 128x128 tile, BK=16, 256 threads, 8x8 per thread.
__global__ __launch_bounds__(256) void sgemm_nt(const float* __restrict__ A,
                                                const float* __restrict__ W,
                                                float* __restrict__ C,
                                                int M, int Ncols, int K) {
    __shared__ __align__(16) float As[16][128];
    __shared__ __align__(16) float Ws[16][128];
    const int t  = threadIdx.x;
    const int tx = t & 15, ty = t >> 4;
    const int row0 = blockIdx.y * 128, col0 = blockIdx.x * 128;
    const int lr = t >> 2;            // 0..63
    const int lk = (t & 3) * 4;       // 0,4,8,12

    float acc[8][8] = {};

    for (int k0 = 0; k0 < K; k0 += 16) {
        #pragma unroll
        for (int p = 0; p < 2; p++) {
            int r  = lr + p * 64;
            int gr = row0 + r;
            float4 v;
            if (gr < M) v = *(const float4*)(A + (size_t)gr * K + k0 + lk);
            else        v = float4{0.f, 0.f, 0.f, 0.f};
            As[lk + 0][r] = v.x; As[lk + 1][r] = v.y; As[lk + 2][r] = v.z; As[lk + 3][r] = v.w;
        }
        #pragma unroll
        for (int p = 0; p < 2; p++) {
            int r  = lr + p * 64;
            int gc = col0 + r;        // Ncols is a multiple of 128 -> always valid
            float4 v = *(const float4*)(W + (size_t)gc * K + k0 + lk);
            Ws[lk + 0][r] = v.x; Ws[lk + 1][r] = v.y; Ws[lk + 2][r] = v.z; Ws[lk + 3][r] = v.w;
        }
        __syncthreads();
        #pragma unroll
        for (int k = 0; k < 16; k++) {
            float4 a0 = *(const float4*)&As[k][ty * 4];
            float4 a1 = *(const float4*)&As[k][64 + ty * 4];
            float4 b0 = *(const float4*)&Ws[k][tx * 4];
            float4 b1 = *(const float4*)&Ws[k][64 + tx * 4];
            float a[8] = {a0.x, a0.y, a0.z, a0.w, a1.x, a1.y, a1.z, a1.w};
            float b[8] = {b0.x, b0.y, b0.z, b0.w, b1.x, b1.y, b1.z, b1.w};
            #pragma unroll
            for (int i = 0; i < 8; i++)
                #pragma unroll
                for (int j = 0; j < 8; j++)
                    acc[i][j] += a[i] * b[j];
        }
        __syncthreads();
    }

    #pragma unroll
    for (int i = 0; i < 8; i++) {
        int gr = row0 + (i < 4 ? ty * 4 + i : 64 + ty * 4 + (i - 4));
        if (gr >= M) continue;
        float* cp = C + (size_t)gr * Ncols + col0;
        float4 v0{acc[i][0], acc[i][1], acc[i][2], acc[i][3]};
        float4 v1{acc[i][4], acc[i][5], acc[i][6], acc[i][7]};
        *(float4*)(cp + tx * 4)      = v0;
        *(float4*)(cp + 64 + tx * 4) = v1;
    }
}

// ---------------- per-(node,head) attention coefficients ----------------
template<int C>
__global__ __launch_bounds__(512) void alphas_k(const float* __restrict__ h,
                                                const float* __restrict__ a_s,
                                                const float* __restrict__ a_d,
                                                float* __restrict__ asrc,
                                                float* __restrict__ adst) {
    int n    = blockIdx.x;
    int hd   = threadIdx.x >> 6;   // 8 waves = 8 heads
    int lane = threadIdx.x & 63;
    const float* hp = h + (size_t)n * (HEADS * C) + hd * C;
    float s1 = 0.f, s2 = 0.f;
    #pragma unroll
    for (int c = lane; c < C; c += 64) {
        float v = hp[c];
        s1 += v * a_s[hd * C + c];
        s2 += v * a_d[hd * C + c];
    }
    #pragma unroll
    for (int off = 32; off; off >>= 1) {
        s1 += __shfl_down(s1, off);
        s2 += __shfl_down(s2, off);
    }
    if (lane == 0) {
        asrc[n * HEADS + hd] = s1;
        adst[n * HEADS + hd] = s2;
    }
}

// ---------------- softmax + aggregation: one wave per (node, head) ----------------
// MODE 0: concat heads, +bias, ELU -> out[N, H*C]
// MODE 1: mean over heads via atomicAdd * 1/8 -> out[N, C]  (bias added later)
template<int C, int MODE>
__global__ __launch_bounds__(256) void agg_k(const float* __restrict__ h,
                                             const float* __restrict__ asrc,
                                             const float* __restrict__ adst,
                                             const int* __restrict__ rows,
                                             const int* __restrict__ esrc,
                                             const float* __restrict__ bias,
                                             float* __restrict__ out) {
    constexpr int V = C / 64;
    int wid  = blockIdx.x * 4 + (threadIdx.x >> 6);
    int lane = threadIdx.x & 63;
    int n  = wid >> 3;
    int hd = wid & 7;
    if (n >= NNODES) return;
    int beg = rows[n], end = rows[n + 1];
    float ad = adst[n * HEADS + hd];

    // pass 1: max
    float m = -1e30f;
    for (int i = beg + lane; i < end; i += 64) {
        float lg = asrc[esrc[i] * HEADS + hd] + ad;
        lg = (lg > 0.f) ? lg : 0.2f * lg;
        m = fmaxf(m, lg);
    }
    #pragma unroll
    for (int off = 32; off; off >>= 1) m = fmaxf(m, __shfl_xor(m, off));

    // pass 2: sum of exp
    float ssum = 0.f;
    for (int i = beg + lane; i < end; i += 64) {
        float lg = asrc[esrc[i] * HEADS + hd] + ad;
        lg = (lg > 0.f) ? lg : 0.2f * lg;
        ssum += __expf(lg - m);
    }
    #pragma unroll
    for (int off = 32; off; off >>= 1) ssum += __shfl_xor(ssum, off);
    float inv = 1.f / (ssum + 1e-16f);

    // pass 3: weighted gather-accumulate
    float acc[V] = {};
    for (int i = beg; i < end; i++) {
        int s = esrc[i];
        float lg = asrc[s * HEADS + hd] + ad;
        lg = (lg > 0.f) ? lg : 0.2f * lg;
        float w = __expf(lg - m) * inv;
        const float* hp = h + (size_t)s * (HEADS * C) + hd * C + lane * V;
        if constexpr (V == 1) {
            acc[0] += w * hp[0];
        } else if constexpr (V == 2) {
            float2 v = *(const float2*)hp;
            acc[0] += w * v.x; acc[1] += w * v.y;
        } else {
            float4 v = *(const float4*)hp;
            acc[0] += w * v.x; acc[1] += w * v.y; acc[2] += w * v.z; acc[3] += w * v.w;
        }
    }

    if constexpr (MODE == 0) {
        const float* bp = bias + hd * C + lane * V;
        float* op = out + (size_t)n * (HEADS * C) + hd * C + lane * V;
        float r[V];
        #pragma unroll
        for (int j = 0; j < V; j++) {
            float v = acc[j] + bp[j];
            r[j] = (v > 0.f) ? v : (expf(v) - 1.f);   // ELU
        }
        if constexpr (V == 1)      { op[0] = r[0]; }
        else if constexpr (V == 2) { *(float2*)op = float2{r[0], r[1]}; }
        else                       { *(float4*)op = float4{r[0], r[1], r[2], r[3]}; }
    } else {
        float* op = out + (size_t)n * C + lane * V;
        #pragma unroll
        for (int j = 0; j < V; j++) atomicAdd(op + j, acc[j] * 0.125f);
    }
}

__global__ void bias3_k(float* __restrict__ out, const float* __restrict__ b3) {
    int i = blockIdx.x * 256 + threadIdx.x;
    if (i < NNODES * 256) out[i] += b3[i & 255];
}

// ---------------- launch ----------------
extern "C" void kernel_launch(void* const* d_in, const int* in_sizes, int n_in,
                              void* d_out, int out_size, void* d_ws, size_t ws_size,
                              hipStream_t stream) {
    const float* x   = (const float*)d_in[0];
    const int*   ei  = (const int*)d_in[1];
    const float* W1  = (const float*)d_in[2];
    const float* as1 = (const float*)d_in[3];
    const float* ad1 = (const float*)d_in[4];
    const float* b1  = (const float*)d_in[5];
    const float* W2  = (const float*)d_in[6];
    const float* as2 = (const float*)d_in[7];
    const float* ad2 = (const float*)d_in[8];
    const float* b2  = (const float*)d_in[9];
    const float* W3  = (const float*)d_in[10];
    const float* as3 = (const float*)d_in[11];
    const float* ad3 = (const float*)d_in[12];
    const float* b3  = (const float*)d_in[13];
    float* out = (float*)d_out;

    // workspace carve-up (all offsets multiples of 16B)
    int* deg    = (int*)d_ws;
    int* cursor = deg + 10240;
    int* rows   = cursor + 10240;
    int* esrc   = rows + 10240;
    float* asrc = (float*)(esrc + 172032);
    float* adst = asrc + 81920;
    float* bufA = adst + 81920;                     // holds h (up to 10000*2048)
    float* bufB = bufA + (size_t)NNODES * 2048;     // holds activations (up to 10000*1024)

    hipMemsetAsync(deg, 0, 2 * 10240 * sizeof(int), stream);        // deg + cursor
    hipMemsetAsync(out, 0, (size_t)out_size * sizeof(float), stream);

    count_k<<<(TOT_E + 255) / 256, 256, 0, stream>>>(ei, deg);
    scan_k<<<1, 256, 0, stream>>>(deg, rows);
    scatter_k<<<(TOT_E + 255) / 256, 256, 0, stream>>>(ei, rows, cursor, esrc);

    const int rowBlocks = (NNODES + 127) / 128;

    // ---- layer 1: IN=256 -> 8x64 concat ----
    sgemm_nt<<<dim3(512 / 128, rowBlocks), 256, 0, stream>>>(x, W1, bufA, NNODES, 512, 256);
    alphas_k<64><<<NNODES, 512, 0, stream>>>(bufA, as1, ad1, asrc, adst);
    agg_k<64, 0><<<NNODES * HEADS / 4, 256, 0, stream>>>(bufA, asrc, adst, rows, esrc, b1, bufB);

    // ---- layer 2: 512 -> 8x128 concat ----
    sgemm_nt<<<dim3(1024 / 128, rowBlocks), 256, 0, stream>>>(bufB, W2, bufA, NNODES, 1024, 512);
    alphas_k<128><<<NNODES, 512, 0, stream>>>(bufA, as2, ad2, asrc, adst);
    agg_k<128, 0><<<NNODES * HEADS / 4, 256, 0, stream>>>(bufA, asrc, adst, rows, esrc, b2, bufB);

    // ---- layer 3: 1024 -> 8x256 mean ----
    sgemm_nt<<<dim3(2048 / 128, rowBlocks), 256, 0, stream>>>(bufB, W3, bufA, NNODES, 2048, 1024);
    alphas_k<256><<<NNODES, 512, 0, stream>>>(bufA, as3, ad3, asrc, adst);
    agg_k<256, 1><<<NNODES * HEADS / 4, 256, 0, stream>>>(bufA, asrc, adst, rows, esrc, nullptr, out);
    bias3_k<<<(NNODES * 256 + 255) / 256, 256, 0, stream>>>(out, b3);
}

// Round 2
// 1071.766 us; speedup vs baseline: 1.5038x; 1.5038x over previous
//
#include <hip/hip_runtime.h>
#include <cstdint>

#define NNODES 10000
#define NEDGES 160000
#define TOT_E  (NEDGES + NNODES)
#define HEADS  8

typedef unsigned short u16;
typedef __attribute__((ext_vector_type(8))) short sh8;   // 8 bf16 in 4 VGPRs
typedef __attribute__((ext_vector_type(4))) float f4;    // MFMA accumulator

__device__ inline u16 f2bf(float x) {                    // round-to-nearest-even fp32->bf16
    union { float f; unsigned u; } v; v.f = x;
    unsigned r = v.u + 0x7fffu + ((v.u >> 16) & 1u);
    return (u16)(r >> 16);
}
__device__ inline float bf2f(u16 b) {
    union { unsigned u; float f; } v; v.u = ((unsigned)b) << 16;
    return v.f;
}

// ---------------- CSR build (dst-sorted) ----------------
__global__ void count_k(const int* __restrict__ ei, int* __restrict__ deg) {
    int i = blockIdx.x * 256 + threadIdx.x;
    if (i >= TOT_E) return;
    int dst = (i < NEDGES) ? ei[NEDGES + i] : (i - NEDGES);
    atomicAdd(deg + dst, 1);
}

__global__ void scan_k(const int* __restrict__ deg, int* __restrict__ rows) {
    __shared__ int buf[256];
    __shared__ int carry;
    if (threadIdx.x == 0) carry = 0;
    __syncthreads();
    for (int base = 0; base < NNODES; base += 256) {
        int i = base + threadIdx.x;
        int v = (i < NNODES) ? deg[i] : 0;
        buf[threadIdx.x] = v;
        __syncthreads();
        for (int off = 1; off < 256; off <<= 1) {
            int t = (threadIdx.x >= off) ? buf[threadIdx.x - off] : 0;
            __syncthreads();
            buf[threadIdx.x] += t;
            __syncthreads();
        }
        if (i < NNODES) rows[i + 1] = carry + buf[threadIdx.x];
        __syncthreads();
        if (threadIdx.x == 255) carry += buf[255];
        __syncthreads();
    }
    if (threadIdx.x == 0) rows[0] = 0;
}

__global__ void scatter_k(const int* __restrict__ ei, const int* __restrict__ rows,
                          int* __restrict__ cursor, int* __restrict__ esrc) {
    int i = blockIdx.x * 256 + threadIdx.x;
    if (i >= TOT_E) return;
    int src, dst;
    if (i < NEDGES) { src = ei[i]; dst = ei[NEDGES + i]; }
    else            { src = i - NEDGES; dst = src; }
    int pos = atomicAdd(cursor + dst, 1);
    esrc[rows[dst] + pos] = src;
}

// ---------------- fp32 -> (hi,lo) bf16 split ----------------
__global__ void split4_k(const float* __restrict__ in, u16* __restrict__ hi,
                         u16* __restrict__ lo, int n4) {
    int i = blockIdx.x * 256 + threadIdx.x;
    if (i >= n4) return;
    float4 v = ((const float4*)in)[i];
    ushort4 h, l;
    h.x = f2bf(v.x); l.x = f2bf(v.x - bf2f(h.x));
    h.y = f2bf(v.y); l.y = f2bf(v.y - bf2f(h.y));
    h.z = f2bf(v.z); l.z = f2bf(v.z - bf2f(h.z));
    h.w = f2bf(v.w); l.w = f2bf(v.w - bf2f(h.w));
    ((ushort4*)hi)[i] = h;
    ((ushort4*)lo)[i] = l;
}

// ---------------- split-bf16 MFMA GEMM: C[M,N] = A[M,K] * W[N,K]^T ----------------
// A,W given as hi/lo bf16 planes (row-major, K contiguous). 128x128 tile, BK=32,
// 4 waves in 2x2, each wave 4x4 tiles of 16x16. 3 MFMAs per tile pair
// (hi*hi + hi*lo + lo*hi) -> fp32-equivalent accuracy.
__global__ __launch_bounds__(256) void gemm_mfma(
    const u16* __restrict__ Ah, const u16* __restrict__ Al,
    const u16* __restrict__ Bh, const u16* __restrict__ Bl,
    float* __restrict__ C, int M, int N, int K)
{
    // row stride 40 ushorts (80B): read phases hit all 32 banks 2-way (free)
    __shared__ u16 sAh[128 * 40], sAl[128 * 40], sBh[128 * 40], sBl[128 * 40];
    const int t = threadIdx.x;
    const int row0 = blockIdx.y * 128, col0 = blockIdx.x * 128;
    const int wid = t >> 6, lane = t & 63;
    const int wm = wid & 1, wn = wid >> 1;
    const int l15 = lane & 15, quad = lane >> 4;

    const int aoff = (wm * 64 + l15) * 40 + quad * 8;
    const int boff = (wn * 64 + l15) * 40 + quad * 8;

    f4 acc[4][4];
    #pragma unroll
    for (int i = 0; i < 4; i++)
        #pragma unroll
        for (int j = 0; j < 4; j++)
            acc[i][j] = (f4){0.f, 0.f, 0.f, 0.f};

    for (int k0 = 0; k0 < K; k0 += 32) {
        #pragma unroll
        for (int p = 0; p < 2; p++) {
            int idx = t + 256 * p;
            int r = idx >> 2, oc = idx & 3;       // 128 rows x 4 octs of 8 ushorts
            size_t goff = (size_t)0;
            int gr = row0 + r;
            uint4 vh = {0u, 0u, 0u, 0u}, vl = {0u, 0u, 0u, 0u};
            if (gr < M) {
                goff = (size_t)gr * K + k0 + oc * 8;
                vh = *(const uint4*)(Ah + goff);
                vl = *(const uint4*)(Al + goff);
            }
            *(uint4*)&sAh[r * 40 + oc * 8] = vh;
            *(uint4*)&sAl[r * 40 + oc * 8] = vl;
            int gc = col0 + r;                    // N multiple of 128 -> in bounds
            goff = (size_t)gc * K + k0 + oc * 8;
            uint4 wh = *(const uint4*)(Bh + goff);
            uint4 wl = *(const uint4*)(Bl + goff);
            *(uint4*)&sBh[r * 40 + oc * 8] = wh;
            *(uint4*)&sBl[r * 40 + oc * 8] = wl;
        }
        __syncthreads();

        sh8 ah[4], al[4];
        #pragma unroll
        for (int i = 0; i < 4; i++) {
            ah[i] = *(const sh8*)&sAh[aoff + i * 16 * 40];
            al[i] = *(const sh8*)&sAl[aoff + i * 16 * 40];
        }
        #pragma unroll
        for (int j = 0; j < 4; j++) {
            sh8 bh = *(const sh8*)&sBh[boff + j * 16 * 40];
            sh8 bl = *(const sh8*)&sBl[boff + j * 16 * 40];
            #pragma unroll
            for (int i = 0; i < 4; i++) {
                acc[i][j] = __builtin_amdgcn_mfma_f32_16x16x32_bf16(ah[i], bh, acc[i][j], 0, 0, 0);
                acc[i][j] = __builtin_amdgcn_mfma_f32_16x16x32_bf16(ah[i], bl, acc[i][j], 0, 0, 0);
                acc[i][j] = __builtin_amdgcn_mfma_f32_16x16x32_bf16(al[i], bh, acc[i][j], 0, 0, 0);
            }
        }
        __syncthreads();
    }

    // epilogue: C/D layout col=lane&15, row=quad*4+reg
    #pragma unroll
    for (int i = 0; i < 4; i++) {
        #pragma unroll
        for (int r = 0; r < 4; r++) {
            int gr = row0 + wm * 64 + i * 16 + quad * 4 + r;
            if (gr >= M) continue;
            float* cp = C + (size_t)gr * N + col0 + wn * 64 + l15;
            #pragma unroll
            for (int j = 0; j < 4; j++)
                cp[j * 16] = acc[i][j][r];
        }
    }
}

// ---------------- per-(node,head) attention coefficients ----------------
template<int C>
__global__ __launch_bounds__(512) void alphas_k(const float* __restrict__ h,
                                                const float* __restrict__ a_s,
                                                const float* __restrict__ a_d,
                                                float* __restrict__ asrc,
                                                float* __restrict__ adst) {
    int n    = blockIdx.x;
    int hd   = threadIdx.x >> 6;
    int lane = threadIdx.x & 63;
    const float* hp = h + (size_t)n * (HEADS * C) + hd * C;
    float s1 = 0.f, s2 = 0.f;
    #pragma unroll
    for (int c = lane; c < C; c += 64) {
        float v = hp[c];
        s1 += v * a_s[hd * C + c];
        s2 += v * a_d[hd * C + c];
    }
    #pragma unroll
    for (int off = 32; off; off >>= 1) {
        s1 += __shfl_down(s1, off);
        s2 += __shfl_down(s2, off);
    }
    if (lane == 0) {
        asrc[n * HEADS + hd] = s1;
        adst[n * HEADS + hd] = s2;
    }
}

// ---------------- softmax + aggregation: one wave per (node, head) ----------------
// MODE 0: concat heads, +bias, ELU, then fp32->(hi,lo) bf16 split -> planes (next GEMM input)
// MODE 1: mean over heads via atomicAdd * 1/8 -> outf[N, C]  (bias added later)
template<int C, int MODE>
__global__ __launch_bounds__(256) void agg_k(const float* __restrict__ h,
                                             const float* __restrict__ asrc,
                                             const float* __restrict__ adst,
                                             const int* __restrict__ rows,
                                             const int* __restrict__ esrc,
                                             const float* __restrict__ bias,
                                             u16* __restrict__ oh,
                                             u16* __restrict__ ol,
                                             float* __restrict__ outf) {
    constexpr int V = C / 64;
    int wid  = blockIdx.x * 4 + (threadIdx.x >> 6);
    int lane = threadIdx.x & 63;
    int n  = wid >> 3;
    int hd = wid & 7;
    if (n >= NNODES) return;
    int beg = rows[n], end = rows[n + 1];
    float ad = adst[n * HEADS + hd];

    float m = -1e30f;
    for (int i = beg + lane; i < end; i += 64) {
        float lg = asrc[esrc[i] * HEADS + hd] + ad;
        lg = (lg > 0.f) ? lg : 0.2f * lg;
        m = fmaxf(m, lg);
    }
    #pragma unroll
    for (int off = 32; off; off >>= 1) m = fmaxf(m, __shfl_xor(m, off));

    float ssum = 0.f;
    for (int i = beg + lane; i < end; i += 64) {
        float lg = asrc[esrc[i] * HEADS + hd] + ad;
        lg = (lg > 0.f) ? lg : 0.2f * lg;
        ssum += __expf(lg - m);
    }
    #pragma unroll
    for (int off = 32; off; off >>= 1) ssum += __shfl_xor(ssum, off);
    float inv = 1.f / (ssum + 1e-16f);

    float acc[V] = {};
    for (int i = beg; i < end; i++) {
        int s = esrc[i];
        float lg = asrc[s * HEADS + hd] + ad;
        lg = (lg > 0.f) ? lg : 0.2f * lg;
        float w = __expf(lg - m) * inv;
        const float* hp = h + (size_t)s * (HEADS * C) + hd * C + lane * V;
        if constexpr (V == 1) {
            acc[0] += w * hp[0];
        } else if constexpr (V == 2) {
            float2 v = *(const float2*)hp;
            acc[0] += w * v.x; acc[1] += w * v.y;
        } else {
            float4 v = *(const float4*)hp;
            acc[0] += w * v.x; acc[1] += w * v.y; acc[2] += w * v.z; acc[3] += w * v.w;
        }
    }

    if constexpr (MODE == 0) {
        const float* bp = bias + hd * C + lane * V;
        size_t base = (size_t)n * (HEADS * C) + hd * C + lane * V;
        #pragma unroll
        for (int j = 0; j < V; j++) {
            float v = acc[j] + bp[j];
            v = (v > 0.f) ? v : (expf(v) - 1.f);   // ELU
            u16 hb = f2bf(v);
            oh[base + j] = hb;
            ol[base + j] = f2bf(v - bf2f(hb));
        }
    } else {
        float* op = outf + (size_t)n * C + lane * V;
        #pragma unroll
        for (int j = 0; j < V; j++) atomicAdd(op + j, acc[j] * 0.125f);
    }
}

__global__ void bias3_k(float* __restrict__ out, const float* __restrict__ b3) {
    int i = blockIdx.x * 256 + threadIdx.x;
    if (i < NNODES * 256) out[i] += b3[i & 255];
}

// ---------------- launch ----------------
extern "C" void kernel_launch(void* const* d_in, const int* in_sizes, int n_in,
                              void* d_out, int out_size, void* d_ws, size_t ws_size,
                              hipStream_t stream) {
    const float* x   = (const float*)d_in[0];
    const int*   ei  = (const int*)d_in[1];
    const float* W1  = (const float*)d_in[2];
    const float* as1 = (const float*)d_in[3];
    const float* ad1 = (const float*)d_in[4];
    const float* b1  = (const float*)d_in[5];
    const float* W2  = (const float*)d_in[6];
    const float* as2 = (const float*)d_in[7];
    const float* ad2 = (const float*)d_in[8];
    const float* b2  = (const float*)d_in[9];
    const float* W3  = (const float*)d_in[10];
    const float* as3 = (const float*)d_in[11];
    const float* ad3 = (const float*)d_in[12];
    const float* b3  = (const float*)d_in[13];
    float* out = (float*)d_out;

    // workspace carve-up (~133 MB)
    int* deg    = (int*)d_ws;                     // 10240
    int* cursor = deg + 10240;                    // 10240
    int* rows   = cursor + 10240;                 // 10240
    int* esrc   = rows + 10240;                   // 170240
    float* asrc = (float*)(esrc + 170240);        // 80128
    float* adst = asrc + 80128;                   // 80128
    float* H    = adst + 80128;                   // 10000*2048 fp32
    u16* Ahg    = (u16*)(H + (size_t)NNODES * 2048);   // 10000*1024 bf16-hi (activations)
    u16* Alg    = Ahg + (size_t)NNODES * 1024;         // bf16-lo
    u16* Whg    = Alg + (size_t)NNODES * 1024;         // 2048*1024 (largest W)
    u16* Wlg    = Whg + (size_t)2048 * 1024;

    hipMemsetAsync(deg, 0, 2 * 10240 * sizeof(int), stream);        // deg + cursor
    hipMemsetAsync(out, 0, (size_t)out_size * sizeof(float), stream);

    count_k<<<(TOT_E + 255) / 256, 256, 0, stream>>>(ei, deg);
    scan_k<<<1, 256, 0, stream>>>(deg, rows);
    scatter_k<<<(TOT_E + 255) / 256, 256, 0, stream>>>(ei, rows, cursor, esrc);

    const int rowBlocks = (NNODES + 127) / 128;   // 79

    // ---- layer 1: IN=256 -> 8x64 concat ----
    split4_k<<<(NNODES * 256 / 4 + 255) / 256, 256, 0, stream>>>(x, Ahg, Alg, NNODES * 256 / 4);
    split4_k<<<(512 * 256 / 4 + 255) / 256, 256, 0, stream>>>(W1, Whg, Wlg, 512 * 256 / 4);
    gemm_mfma<<<dim3(4, rowBlocks), 256, 0, stream>>>(Ahg, Alg, Whg, Wlg, H, NNODES, 512, 256);
    alphas_k<64><<<NNODES, 512, 0, stream>>>(H, as1, ad1, asrc, adst);
    agg_k<64, 0><<<NNODES * HEADS / 4, 256, 0, stream>>>(H, asrc, adst, rows, esrc, b1, Ahg, Alg, nullptr);

    // ---- layer 2: 512 -> 8x128 concat ----
    split4_k<<<(1024 * 512 / 4 + 255) / 256, 256, 0, stream>>>(W2, Whg, Wlg, 1024 * 512 / 4);
    gemm_mfma<<<dim3(8, rowBlocks), 256, 0, stream>>>(Ahg, Alg, Whg, Wlg, H, NNODES, 1024, 512);
    alphas_k<128><<<NNODES, 512, 0, stream>>>(H, as2, ad2, asrc, adst);
    agg_k<128, 0><<<NNODES * HEADS / 4, 256, 0, stream>>>(H, asrc, adst, rows, esrc, b2, Ahg, Alg, nullptr);

    // ---- layer 3: 1024 -> 8x256 mean ----
    split4_k<<<(2048 * 1024 / 4 + 255) / 256, 256, 0, stream>>>(W3, Whg, Wlg, 2048 * 1024 / 4);
    gemm_mfma<<<dim3(16, rowBlocks), 256, 0, stream>>>(Ahg, Alg, Whg, Wlg, H, NNODES, 2048, 1024);
    alphas_k<256><<<NNODES, 512, 0, stream>>>(H, as3, ad3, asrc, adst);
    agg_k<256, 1><<<NNODES * HEADS / 4, 256, 0, stream>>>(H, asrc, adst, rows, esrc, nullptr, nullptr, nullptr, out);
    bias3_k<<<(NNODES * 256 + 255) / 256, 256, 0, stream>>>(out, b3);
}

// Round 3
// 847.026 us; speedup vs baseline: 1.9028x; 1.2653x over previous
//
#include <hip/hip_runtime.h>
#include <cstdint>

#define NNODES 10000
#define NEDGES 160000
#define TOT_E  (NEDGES + NNODES)
#define HEADS  8

typedef unsigned short u16;
typedef __attribute__((ext_vector_type(8))) short sh8;   // 8 bf16 in 4 VGPRs
typedef __attribute__((ext_vector_type(4))) float f4;    // MFMA accumulator

__device__ inline u16 f2bf(float x) {                    // RNE fp32->bf16
    union { float f; unsigned u; } v; v.f = x;
    unsigned r = v.u + 0x7fffu + ((v.u >> 16) & 1u);
    return (u16)(r >> 16);
}
__device__ inline float bf2f(u16 b) {
    union { unsigned u; float f; } v; v.u = ((unsigned)b) << 16;
    return v.f;
}

__device__ inline void gld16(const u16* g, u16* l) {
    __builtin_amdgcn_global_load_lds(
        (const __attribute__((address_space(1))) void*)g,
        (__attribute__((address_space(3))) void*)l, 16, 0, 0);
}

// ---------------- CSR build (dst-sorted) ----------------
__global__ void count_k(const int* __restrict__ ei, int* __restrict__ deg) {
    int i = blockIdx.x * 256 + threadIdx.x;
    if (i >= TOT_E) return;
    int dst = (i < NEDGES) ? ei[NEDGES + i] : (i - NEDGES);
    atomicAdd(deg + dst, 1);
}

// single-pass scan: 1024 threads x 10 elements each
__global__ __launch_bounds__(1024) void scan_k(const int* __restrict__ deg,
                                               int* __restrict__ rows) {
    __shared__ int buf[1024];
    int tid = threadIdx.x;
    int base = tid * 10;
    int loc[10]; int s = 0;
    #pragma unroll
    for (int j = 0; j < 10; j++) {
        int i = base + j;
        loc[j] = s;
        s += (i < NNODES) ? deg[i] : 0;
    }
    buf[tid] = s;
    __syncthreads();
    for (int off = 1; off < 1024; off <<= 1) {
        int t = (tid >= off) ? buf[tid - off] : 0;
        __syncthreads();
        buf[tid] += t;
        __syncthreads();
    }
    int ex = tid ? buf[tid - 1] : 0;
    #pragma unroll
    for (int j = 0; j < 10; j++) {
        int i = base + j;
        if (i < NNODES) rows[i] = ex + loc[j];
    }
    if (tid == 1023) rows[NNODES] = buf[1023];
}

__global__ void scatter_k(const int* __restrict__ ei, const int* __restrict__ rows,
                          int* __restrict__ cursor, int* __restrict__ esrc) {
    int i = blockIdx.x * 256 + threadIdx.x;
    if (i >= TOT_E) return;
    int src, dst;
    if (i < NEDGES) { src = ei[i]; dst = ei[NEDGES + i]; }
    else            { src = i - NEDGES; dst = src; }
    int pos = atomicAdd(cursor + dst, 1);
    esrc[rows[dst] + pos] = src;
}

// ---------------- fp32 -> (hi,lo) bf16 split ----------------
__global__ void split4_k(const float* __restrict__ in, u16* __restrict__ hi,
                         u16* __restrict__ lo, int n4) {
    int i = blockIdx.x * 256 + threadIdx.x;
    if (i >= n4) return;
    float4 v = ((const float4*)in)[i];
    ushort4 h, l;
    h.x = f2bf(v.x); l.x = f2bf(v.x - bf2f(h.x));
    h.y = f2bf(v.y); l.y = f2bf(v.y - bf2f(h.y));
    h.z = f2bf(v.z); l.z = f2bf(v.z - bf2f(h.z));
    h.w = f2bf(v.w); l.w = f2bf(v.w - bf2f(h.w));
    ((ushort4*)hi)[i] = h;
    ((ushort4*)lo)[i] = l;
}

// ---------------- split-bf16 MFMA GEMM: C[M,N] = A[M,K] * W[N,K]^T ----------------
// global_load_lds (16B) staging into unpadded [128 x 32] bf16 tiles; 128x128 tile,
// BK=32, 4 waves 2x2, 4x4 16x16 tiles/wave, 3 MFMAs per hi/lo pair.
__global__ __launch_bounds__(256) void gemm_mfma(
    const u16* __restrict__ Ah, const u16* __restrict__ Al,
    const u16* __restrict__ Bh, const u16* __restrict__ Bl,
    float* __restrict__ C, int M, int N, int K)
{
    __shared__ u16 sAh[4096], sAl[4096], sBh[4096], sBl[4096];   // 8KB each
    const int t = threadIdx.x, lane = t & 63, w = t >> 6;
    const int row0 = blockIdx.y * 128, col0 = blockIdx.x * 128;
    const int wm = w & 1, wn = w >> 1;
    const int l15 = lane & 15, quad = lane >> 4;

    // staging: wave w handles chunks c=2w,2w+1; chunk c = rows [16c,16c+16),
    // lane covers row 16c+(lane>>2), oct lane&3 (16B). LDS slot = base + lane*16.
    const int rs0 = (w * 2) * 16 + (lane >> 2);
    const int rs1 = (w * 2 + 1) * 16 + (lane >> 2);
    const int oct = lane & 3;
    int ga0 = row0 + rs0; if (ga0 >= M) ga0 = M - 1;
    int ga1 = row0 + rs1; if (ga1 >= M) ga1 = M - 1;
    const int gb0 = col0 + rs0, gb1 = col0 + rs1;   // N mult of 128 -> in bounds
    const u16* pA0h = Ah + (size_t)ga0 * K + oct * 8;
    const u16* pA1h = Ah + (size_t)ga1 * K + oct * 8;
    const u16* pA0l = Al + (size_t)ga0 * K + oct * 8;
    const u16* pA1l = Al + (size_t)ga1 * K + oct * 8;
    const u16* pB0h = Bh + (size_t)gb0 * K + oct * 8;
    const u16* pB1h = Bh + (size_t)gb1 * K + oct * 8;
    const u16* pB0l = Bl + (size_t)gb0 * K + oct * 8;
    const u16* pB1l = Bl + (size_t)gb1 * K + oct * 8;
    const int cb0 = (w * 2) * 512, cb1 = (w * 2 + 1) * 512;   // u16 index of chunk base

    const int aoff = (wm * 64 + l15) * 32 + quad * 8;
    const int boff = (wn * 64 + l15) * 32 + quad * 8;

    f4 acc[4][4];
    #pragma unroll
    for (int i = 0; i < 4; i++)
        #pragma unroll
        for (int j = 0; j < 4; j++)
            acc[i][j] = (f4){0.f, 0.f, 0.f, 0.f};

    for (int k0 = 0; k0 < K; k0 += 32) {
        gld16(pA0h, &sAh[cb0]); gld16(pA1h, &sAh[cb1]);
        gld16(pA0l, &sAl[cb0]); gld16(pA1l, &sAl[cb1]);
        gld16(pB0h, &sBh[cb0]); gld16(pB1h, &sBh[cb1]);
        gld16(pB0l, &sBl[cb0]); gld16(pB1l, &sBl[cb1]);
        pA0h += 32; pA1h += 32; pA0l += 32; pA1l += 32;
        pB0h += 32; pB1h += 32; pB0l += 32; pB1l += 32;
        __syncthreads();   // drains vmcnt (global_load_lds) before ds_read

        sh8 ah[4], al[4];
        #pragma unroll
        for (int i = 0; i < 4; i++) {
            ah[i] = *(const sh8*)&sAh[aoff + i * 512];
            al[i] = *(const sh8*)&sAl[aoff + i * 512];
        }
        #pragma unroll
        for (int j = 0; j < 4; j++) {
            sh8 bh = *(const sh8*)&sBh[boff + j * 512];
            sh8 bl = *(const sh8*)&sBl[boff + j * 512];
            #pragma unroll
            for (int i = 0; i < 4; i++) {
                acc[i][j] = __builtin_amdgcn_mfma_f32_16x16x32_bf16(ah[i], bh, acc[i][j], 0, 0, 0);
                acc[i][j] = __builtin_amdgcn_mfma_f32_16x16x32_bf16(ah[i], bl, acc[i][j], 0, 0, 0);
                acc[i][j] = __builtin_amdgcn_mfma_f32_16x16x32_bf16(al[i], bh, acc[i][j], 0, 0, 0);
            }
        }
        __syncthreads();
    }

    // C/D layout: col=lane&15, row=quad*4+reg
    #pragma unroll
    for (int i = 0; i < 4; i++) {
        #pragma unroll
        for (int r = 0; r < 4; r++) {
            int gr = row0 + wm * 64 + i * 16 + quad * 4 + r;
            if (gr >= M) continue;
            float* cp = C + (size_t)gr * N + col0 + wn * 64 + l15;
            #pragma unroll
            for (int j = 0; j < 4; j++)
                cp[j * 16] = acc[i][j][r];
        }
    }
}

// ---------------- per-(node,head) attention coefficients ----------------
template<int C>
__global__ __launch_bounds__(512) void alphas_k(const float* __restrict__ h,
                                                const float* __restrict__ a_s,
                                                const float* __restrict__ a_d,
                                                float* __restrict__ asrc,
                                                float* __restrict__ adst) {
    constexpr int V = C / 64;
    int n    = blockIdx.x;
    int hd   = threadIdx.x >> 6;
    int lane = threadIdx.x & 63;
    const float* hp = h + (size_t)n * (HEADS * C) + hd * C + lane * V;
    const float* sp = a_s + hd * C + lane * V;
    const float* dp = a_d + hd * C + lane * V;
    float s1 = 0.f, s2 = 0.f;
    if constexpr (V == 1) {
        float v = hp[0]; s1 = v * sp[0]; s2 = v * dp[0];
    } else if constexpr (V == 2) {
        float2 v = *(const float2*)hp, a = *(const float2*)sp, b = *(const float2*)dp;
        s1 = v.x * a.x + v.y * a.y; s2 = v.x * b.x + v.y * b.y;
    } else {
        float4 v = *(const float4*)hp, a = *(const float4*)sp, b = *(const float4*)dp;
        s1 = v.x * a.x + v.y * a.y + v.z * a.z + v.w * a.w;
        s2 = v.x * b.x + v.y * b.y + v.z * b.z + v.w * b.w;
    }
    #pragma unroll
    for (int off = 32; off; off >>= 1) {
        s1 += __shfl_down(s1, off);
        s2 += __shfl_down(s2, off);
    }
    if (lane == 0) {
        asrc[n * HEADS + hd] = s1;
        adst[n * HEADS + hd] = s2;
    }
}

// ---------------- softmax + aggregation: one wave per (node, head) ----------------
// No max-subtraction (logits bounded ~+-10; p/s scale-invariant). Fast path deg<=64:
// per-edge p held lane-parallel in registers, single h-gather pass unrolled x4.
// MODE 0: +bias, ELU, fp32->(hi,lo) bf16 split. MODE 1: mean-head atomicAdd into
// out pre-initialized with bias.
template<int C, int MODE>
__global__ __launch_bounds__(256) void agg_k(const float* __restrict__ h,
                                             const float* __restrict__ asrc,
                                             const float* __restrict__ adst,
                                             const int* __restrict__ rows,
                                             const int* __restrict__ esrc,
                                             const float* __restrict__ bias,
                                             u16* __restrict__ oh,
                                             u16* __restrict__ ol,
                                             float* __restrict__ outf) {
    constexpr int V = C / 64;
    int wid  = blockIdx.x * 4 + (threadIdx.x >> 6);
    int lane = threadIdx.x & 63;
    int n  = wid >> 3;
    int hd = wid & 7;
    if (n >= NNODES) return;
    int beg = rows[n], end = rows[n + 1];
    int deg = end - beg;
    float ad = adst[n * HEADS + hd];

    float acc[V] = {};

    if (deg <= 64) {
        int e = 0; float p = 0.f;
        if (lane < deg) {
            e = esrc[beg + lane];
            float lg = asrc[e * HEADS + hd] + ad;
            lg = (lg > 0.f) ? lg : 0.2f * lg;
            p = __expf(lg);
        }
        float s = p;
        #pragma unroll
        for (int off = 32; off; off >>= 1) s += __shfl_xor(s, off);
        float pw = p / (s + 1e-16f);          // 0 for padding lanes

        int deg4 = (deg + 3) & ~3;
        for (int j = 0; j < deg4; j += 4) {
            #pragma unroll
            for (int u = 0; u < 4; u++) {
                int sn    = __shfl(e, j + u);     // padding: sn=0, wgt=0 (safe)
                float wgt = __shfl(pw, j + u);
                const float* hp = h + (size_t)sn * (HEADS * C) + hd * C + lane * V;
                if constexpr (V == 1) {
                    acc[0] += wgt * hp[0];
                } else if constexpr (V == 2) {
                    float2 v = *(const float2*)hp;
                    acc[0] += wgt * v.x; acc[1] += wgt * v.y;
                } else {
                    float4 v = *(const float4*)hp;
                    acc[0] += wgt * v.x; acc[1] += wgt * v.y;
                    acc[2] += wgt * v.z; acc[3] += wgt * v.w;
                }
            }
        }
    } else {
        // rare general path (deg > 64)
        float ssum = 0.f;
        for (int i = beg + lane; i < end; i += 64) {
            float lg = asrc[esrc[i] * HEADS + hd] + ad;
            lg = (lg > 0.f) ? lg : 0.2f * lg;
            ssum += __expf(lg);
        }
        #pragma unroll
        for (int off = 32; off; off >>= 1) ssum += __shfl_xor(ssum, off);
        float inv = 1.f / (ssum + 1e-16f);
        for (int i = beg; i < end; i++) {
            int sn = esrc[i];
            float lg = asrc[sn * HEADS + hd] + ad;
            lg = (lg > 0.f) ? lg : 0.2f * lg;
            float wgt = __expf(lg) * inv;
            const float* hp = h + (size_t)sn * (HEADS * C) + hd * C + lane * V;
            #pragma unroll
            for (int j = 0; j < V; j++) acc[j] += wgt * hp[j];
        }
    }

    if constexpr (MODE == 0) {
        const float* bp = bias + hd * C + lane * V;
        size_t base = (size_t)n * (HEADS * C) + hd * C + lane * V;
        #pragma unroll
        for (int j = 0; j < V; j++) {
            float v = acc[j] + bp[j];
            v = (v > 0.f) ? v : (expf(v) - 1.f);   // ELU
            u16 hb = f2bf(v);
            oh[base + j] = hb;
            ol[base + j] = f2bf(v - bf2f(hb));
        }
    } else {
        float* op = outf + (size_t)n * C + lane * V;
        #pragma unroll
        for (int j = 0; j < V; j++) atomicAdd(op + j, acc[j] * 0.125f);
    }
}

__global__ void initout_k(float* __restrict__ out, const float* __restrict__ b3) {
    int i = blockIdx.x * 256 + threadIdx.x;
    if (i < NNODES * 256) out[i] = b3[i & 255];
}

// ---------------- launch ----------------
extern "C" void kernel_launch(void* const* d_in, const int* in_sizes, int n_in,
                              void* d_out, int out_size, void* d_ws, size_t ws_size,
                              hipStream_t stream) {
    const float* x   = (const float*)d_in[0];
    const int*   ei  = (const int*)d_in[1];
    const float* W1  = (const float*)d_in[2];
    const float* as1 = (const float*)d_in[3];
    const float* ad1 = (const float*)d_in[4];
    const float* b1  = (const float*)d_in[5];
    const float* W2  = (const float*)d_in[6];
    const float* as2 = (const float*)d_in[7];
    const float* ad2 = (const float*)d_in[8];
    const float* b2  = (const float*)d_in[9];
    const float* W3  = (const float*)d_in[10];
    const float* as3 = (const float*)d_in[11];
    const float* ad3 = (const float*)d_in[12];
    const float* b3  = (const float*)d_in[13];
    float* out = (float*)d_out;

    int* deg    = (int*)d_ws;                     // 10240
    int* cursor = deg + 10240;                    // 10240
    int* rows   = cursor + 10240;                 // 10240
    int* esrc   = rows + 10240;                   // 170240
    float* asrc = (float*)(esrc + 170240);        // 81920
    float* adst = asrc + 81920;                   // 81920
    float* H    = adst + 81920;                   // 10000*2048 fp32
    u16* Ahg    = (u16*)(H + (size_t)NNODES * 2048);
    u16* Alg    = Ahg + (size_t)NNODES * 1024;
    u16* Whg    = Alg + (size_t)NNODES * 1024;
    u16* Wlg    = Whg + (size_t)2048 * 1024;

    hipMemsetAsync(deg, 0, 2 * 10240 * sizeof(int), stream);   // deg + cursor

    count_k<<<(TOT_E + 255) / 256, 256, 0, stream>>>(ei, deg);
    scan_k<<<1, 1024, 0, stream>>>(deg, rows);
    scatter_k<<<(TOT_E + 255) / 256, 256, 0, stream>>>(ei, rows, cursor, esrc);

    const int rowBlocks = (NNODES + 127) / 128;   // 79

    // ---- layer 1: IN=256 -> 8x64 concat ----
    split4_k<<<(NNODES * 256 / 4 + 255) / 256, 256, 0, stream>>>(x, Ahg, Alg, NNODES * 256 / 4);
    split4_k<<<(512 * 256 / 4 + 255) / 256, 256, 0, stream>>>(W1, Whg, Wlg, 512 * 256 / 4);
    gemm_mfma<<<dim3(4, rowBlocks), 256, 0, stream>>>(Ahg, Alg, Whg, Wlg, H, NNODES, 512, 256);
    alphas_k<64><<<NNODES, 512, 0, stream>>>(H, as1, ad1, asrc, adst);
    agg_k<64, 0><<<NNODES * HEADS / 4, 256, 0, stream>>>(H, asrc, adst, rows, esrc, b1, Ahg, Alg, nullptr);

    // ---- layer 2: 512 -> 8x128 concat ----
    split4_k<<<(1024 * 512 / 4 + 255) / 256, 256, 0, stream>>>(W2, Whg, Wlg, 1024 * 512 / 4);
    gemm_mfma<<<dim3(8, rowBlocks), 256, 0, stream>>>(Ahg, Alg, Whg, Wlg, H, NNODES, 1024, 512);
    alphas_k<128><<<NNODES, 512, 0, stream>>>(H, as2, ad2, asrc, adst);
    agg_k<128, 0><<<NNODES * HEADS / 4, 256, 0, stream>>>(H, asrc, adst, rows, esrc, b2, Ahg, Alg, nullptr);

    // ---- layer 3: 1024 -> 8x256 mean ----
    split4_k<<<(2048 * 1024 / 4 + 255) / 256, 256, 0, stream>>>(W3, Whg, Wlg, 2048 * 1024 / 4);
    gemm_mfma<<<dim3(16, rowBlocks), 256, 0, stream>>>(Ahg, Alg, Whg, Wlg, H, NNODES, 2048, 1024);
    alphas_k<256><<<NNODES, 512, 0, stream>>>(H, as3, ad3, asrc, adst);
    initout_k<<<(NNODES * 256 + 255) / 256, 256, 0, stream>>>(out, b3);
    agg_k<256, 1><<<NNODES * HEADS / 4, 256, 0, stream>>>(H, asrc, adst, rows, esrc, nullptr, nullptr, nullptr, out);
}

// Round 4
// 710.409 us; speedup vs baseline: 2.2687x; 1.1923x over previous
//
#include <hip/hip_runtime.h>
#include <cstdint>

#define NNODES 10000
#define NEDGES 160000
#define TOT_E  (NEDGES + NNODES)
#define HEADS  8

typedef unsigned short u16;
typedef __attribute__((ext_vector_type(8))) short sh8;   // 8 bf16 in 4 VGPRs
typedef __attribute__((ext_vector_type(4))) float f4;    // MFMA accumulator

__device__ inline u16 f2bf(float x) {                    // RNE fp32->bf16
    union { float f; unsigned u; } v; v.f = x;
    unsigned r = v.u + 0x7fffu + ((v.u >> 16) & 1u);
    return (u16)(r >> 16);
}
__device__ inline float bf2f(u16 b) {
    union { unsigned u; float f; } v; v.u = ((unsigned)b) << 16;
    return v.f;
}

__device__ inline void gld16(const u16* g, u16* l) {
    __builtin_amdgcn_global_load_lds(
        (const __attribute__((address_space(1))) void*)g,
        (__attribute__((address_space(3))) void*)l, 16, 0, 0);
}

// ---------------- CSR build (dst-sorted) ----------------
__global__ void count_k(const int* __restrict__ ei, int* __restrict__ deg) {
    int i = blockIdx.x * 256 + threadIdx.x;
    if (i >= TOT_E) return;
    int dst = (i < NEDGES) ? ei[NEDGES + i] : (i - NEDGES);
    atomicAdd(deg + dst, 1);
}

__global__ __launch_bounds__(1024) void scan_k(const int* __restrict__ deg,
                                               int* __restrict__ rows) {
    __shared__ int buf[1024];
    int tid = threadIdx.x;
    int base = tid * 10;
    int loc[10]; int s = 0;
    #pragma unroll
    for (int j = 0; j < 10; j++) {
        int i = base + j;
        loc[j] = s;
        s += (i < NNODES) ? deg[i] : 0;
    }
    buf[tid] = s;
    __syncthreads();
    for (int off = 1; off < 1024; off <<= 1) {
        int t = (tid >= off) ? buf[tid - off] : 0;
        __syncthreads();
        buf[tid] += t;
        __syncthreads();
    }
    int ex = tid ? buf[tid - 1] : 0;
    #pragma unroll
    for (int j = 0; j < 10; j++) {
        int i = base + j;
        if (i < NNODES) rows[i] = ex + loc[j];
    }
    if (tid == 1023) rows[NNODES] = buf[1023];
}

__global__ void scatter_k(const int* __restrict__ ei, const int* __restrict__ rows,
                          int* __restrict__ cursor, int* __restrict__ esrc) {
    int i = blockIdx.x * 256 + threadIdx.x;
    if (i >= TOT_E) return;
    int src, dst;
    if (i < NEDGES) { src = ei[i]; dst = ei[NEDGES + i]; }
    else            { src = i - NEDGES; dst = src; }
    int pos = atomicAdd(cursor + dst, 1);
    esrc[rows[dst] + pos] = src;
}

// ---------------- fp32 -> (hi,lo) bf16 split ----------------
__global__ void split4_k(const float* __restrict__ in, u16* __restrict__ hi,
                         u16* __restrict__ lo, int n4) {
    int i = blockIdx.x * 256 + threadIdx.x;
    if (i >= n4) return;
    float4 v = ((const float4*)in)[i];
    ushort4 h, l;
    h.x = f2bf(v.x); l.x = f2bf(v.x - bf2f(h.x));
    h.y = f2bf(v.y); l.y = f2bf(v.y - bf2f(h.y));
    h.z = f2bf(v.z); l.z = f2bf(v.z - bf2f(h.z));
    h.w = f2bf(v.w); l.w = f2bf(v.w - bf2f(h.w));
    ((ushort4*)hi)[i] = h;
    ((ushort4*)lo)[i] = l;
}

// ---------------- split-bf16 MFMA GEMM: C[M,N] = A[M,K] * W[N,K]^T ----------------
__global__ __launch_bounds__(256) void gemm_mfma(
    const u16* __restrict__ Ah, const u16* __restrict__ Al,
    const u16* __restrict__ Bh, const u16* __restrict__ Bl,
    float* __restrict__ C, int M, int N, int K)
{
    __shared__ u16 sAh[4096], sAl[4096], sBh[4096], sBl[4096];
    const int t = threadIdx.x, lane = t & 63, w = t >> 6;
    const int row0 = blockIdx.y * 128, col0 = blockIdx.x * 128;
    const int wm = w & 1, wn = w >> 1;
    const int l15 = lane & 15, quad = lane >> 4;

    const int rs0 = (w * 2) * 16 + (lane >> 2);
    const int rs1 = (w * 2 + 1) * 16 + (lane >> 2);
    const int oct = lane & 3;
    int ga0 = row0 + rs0; if (ga0 >= M) ga0 = M - 1;
    int ga1 = row0 + rs1; if (ga1 >= M) ga1 = M - 1;
    const int gb0 = col0 + rs0, gb1 = col0 + rs1;
    const u16* pA0h = Ah + (size_t)ga0 * K + oct * 8;
    const u16* pA1h = Ah + (size_t)ga1 * K + oct * 8;
    const u16* pA0l = Al + (size_t)ga0 * K + oct * 8;
    const u16* pA1l = Al + (size_t)ga1 * K + oct * 8;
    const u16* pB0h = Bh + (size_t)gb0 * K + oct * 8;
    const u16* pB1h = Bh + (size_t)gb1 * K + oct * 8;
    const u16* pB0l = Bl + (size_t)gb0 * K + oct * 8;
    const u16* pB1l = Bl + (size_t)gb1 * K + oct * 8;
    const int cb0 = (w * 2) * 512, cb1 = (w * 2 + 1) * 512;

    const int aoff = (wm * 64 + l15) * 32 + quad * 8;
    const int boff = (wn * 64 + l15) * 32 + quad * 8;

    f4 acc[4][4];
    #pragma unroll
    for (int i = 0; i < 4; i++)
        #pragma unroll
        for (int j = 0; j < 4; j++)
            acc[i][j] = (f4){0.f, 0.f, 0.f, 0.f};

    for (int k0 = 0; k0 < K; k0 += 32) {
        gld16(pA0h, &sAh[cb0]); gld16(pA1h, &sAh[cb1]);
        gld16(pA0l, &sAl[cb0]); gld16(pA1l, &sAl[cb1]);
        gld16(pB0h, &sBh[cb0]); gld16(pB1h, &sBh[cb1]);
        gld16(pB0l, &sBl[cb0]); gld16(pB1l, &sBl[cb1]);
        pA0h += 32; pA1h += 32; pA0l += 32; pA1l += 32;
        pB0h += 32; pB1h += 32; pB0l += 32; pB1l += 32;
        __syncthreads();

        sh8 ah[4], al[4];
        #pragma unroll
        for (int i = 0; i < 4; i++) {
            ah[i] = *(const sh8*)&sAh[aoff + i * 512];
            al[i] = *(const sh8*)&sAl[aoff + i * 512];
        }
        #pragma unroll
        for (int j = 0; j < 4; j++) {
            sh8 bh = *(const sh8*)&sBh[boff + j * 512];
            sh8 bl = *(const sh8*)&sBl[boff + j * 512];
            #pragma unroll
            for (int i = 0; i < 4; i++) {
                acc[i][j] = __builtin_amdgcn_mfma_f32_16x16x32_bf16(ah[i], bh, acc[i][j], 0, 0, 0);
                acc[i][j] = __builtin_amdgcn_mfma_f32_16x16x32_bf16(ah[i], bl, acc[i][j], 0, 0, 0);
                acc[i][j] = __builtin_amdgcn_mfma_f32_16x16x32_bf16(al[i], bh, acc[i][j], 0, 0, 0);
            }
        }
        __syncthreads();
    }

    #pragma unroll
    for (int i = 0; i < 4; i++) {
        #pragma unroll
        for (int r = 0; r < 4; r++) {
            int gr = row0 + wm * 64 + i * 16 + quad * 4 + r;
            if (gr >= M) continue;
            float* cp = C + (size_t)gr * N + col0 + wn * 64 + l15;
            #pragma unroll
            for (int j = 0; j < 4; j++)
                cp[j * 16] = acc[i][j][r];
        }
    }
}

// ---------------- per-(node,head) attention coefficients ----------------
template<int C>
__global__ __launch_bounds__(512) void alphas_k(const float* __restrict__ h,
                                                const float* __restrict__ a_s,
                                                const float* __restrict__ a_d,
                                                float* __restrict__ asrc,
                                                float* __restrict__ adst) {
    constexpr int V = C / 64;
    int n    = blockIdx.x;
    int hd   = threadIdx.x >> 6;
    int lane = threadIdx.x & 63;
    const float* hp = h + (size_t)n * (HEADS * C) + hd * C + lane * V;
    const float* sp = a_s + hd * C + lane * V;
    const float* dp = a_d + hd * C + lane * V;
    float s1 = 0.f, s2 = 0.f;
    if constexpr (V == 1) {
        float v = hp[0]; s1 = v * sp[0]; s2 = v * dp[0];
    } else if constexpr (V == 2) {
        float2 v = *(const float2*)hp, a = *(const float2*)sp, b = *(const float2*)dp;
        s1 = v.x * a.x + v.y * a.y; s2 = v.x * b.x + v.y * b.y;
    } else {
        float4 v = *(const float4*)hp, a = *(const float4*)sp, b = *(const float4*)dp;
        s1 = v.x * a.x + v.y * a.y + v.z * a.z + v.w * a.w;
        s2 = v.x * b.x + v.y * b.y + v.z * b.z + v.w * b.w;
    }
    #pragma unroll
    for (int off = 32; off; off >>= 1) {
        s1 += __shfl_down(s1, off);
        s2 += __shfl_down(s2, off);
    }
    if (lane == 0) {
        asrc[n * HEADS + hd] = s1;
        adst[n * HEADS + hd] = s2;
    }
}

// ---------------- softmax + aggregation ----------------
// One block per node, 8 waves = 8 heads. No max-subtraction (logits bounded;
// p/s scale-invariant). LPE = C/4 lanes per edge (always float4 loads),
// EPW = 64/LPE edges per pass, U=8 passes in flight -> 8 outstanding 16B
// loads/lane. Out-of-range slots masked to (src=0, w=0) -> cached row.
// MODE 0: concat +bias +ELU + bf16 hi/lo split. MODE 1: LDS head-mean + bias,
// single coalesced store (no atomics).
template<int C, int MODE>
__global__ __launch_bounds__(512) void agg_k(const float* __restrict__ h,
                                             const float* __restrict__ asrc,
                                             const float* __restrict__ adst,
                                             const int* __restrict__ rows,
                                             const int* __restrict__ esrc,
                                             const float* __restrict__ bias,
                                             u16* __restrict__ oh,
                                             u16* __restrict__ ol,
                                             float* __restrict__ outf) {
    constexpr int LPE = C / 4;
    constexpr int EPW = 64 / LPE;
    constexpr int U   = 8;
    __shared__ float red[MODE == 1 ? HEADS * 256 : 8];

    const int n    = blockIdx.x;
    const int hd   = threadIdx.x >> 6;
    const int lane = threadIdx.x & 63;
    const int sub  = lane / LPE;
    const int cl   = lane % LPE;
    const int beg = rows[n], end = rows[n + 1], deg = end - beg;
    const float ad = adst[n * HEADS + hd];

    float4 acc = {0.f, 0.f, 0.f, 0.f};

    auto gather = [&](int e, float pw, int cdeg) {
        for (int j = 0; j < cdeg; j += EPW * U) {
            int   sn[U]; float wg[U];
            #pragma unroll
            for (int u = 0; u < U; u++) {
                int idx = j + sub + EPW * u;
                int   ss = __shfl(e, idx);
                float ww = __shfl(pw, idx);
                bool ok = idx < cdeg;
                sn[u] = ok ? ss : 0;
                wg[u] = ok ? ww : 0.f;
            }
            float4 v[U];
            #pragma unroll
            for (int u = 0; u < U; u++)
                v[u] = *(const float4*)(h + (size_t)sn[u] * (HEADS * C) + hd * C + cl * 4);
            #pragma unroll
            for (int u = 0; u < U; u++) {
                acc.x += wg[u] * v[u].x; acc.y += wg[u] * v[u].y;
                acc.z += wg[u] * v[u].z; acc.w += wg[u] * v[u].w;
            }
        }
    };

    if (deg <= 64) {
        int e = 0; float p = 0.f;
        if (lane < deg) {
            e = esrc[beg + lane];
            float lg = asrc[e * HEADS + hd] + ad;
            lg = (lg > 0.f) ? lg : 0.2f * lg;
            p = __expf(lg);
        }
        float s = p;
        #pragma unroll
        for (int off = 32; off; off >>= 1) s += __shfl_xor(s, off);
        float pw = p / (s + 1e-16f);
        gather(e, pw, deg);
    } else {
        float ssum = 0.f;
        for (int i = beg + lane; i < end; i += 64) {
            float lg = asrc[esrc[i] * HEADS + hd] + ad;
            lg = (lg > 0.f) ? lg : 0.2f * lg;
            ssum += __expf(lg);
        }
        #pragma unroll
        for (int off = 32; off; off >>= 1) ssum += __shfl_xor(ssum, off);
        float inv = 1.f / (ssum + 1e-16f);
        for (int c0 = beg; c0 < end; c0 += 64) {
            int cdeg = min(64, end - c0);
            int e = 0; float pw = 0.f;
            if (lane < cdeg) {
                e = esrc[c0 + lane];
                float lg = asrc[e * HEADS + hd] + ad;
                lg = (lg > 0.f) ? lg : 0.2f * lg;
                pw = __expf(lg) * inv;
            }
            gather(e, pw, cdeg);
        }
    }

    // reduce across sub-groups (edges processed by different lane groups)
    #pragma unroll
    for (int m = LPE; m < 64; m <<= 1) {
        acc.x += __shfl_xor(acc.x, m); acc.y += __shfl_xor(acc.y, m);
        acc.z += __shfl_xor(acc.z, m); acc.w += __shfl_xor(acc.w, m);
    }

    if constexpr (MODE == 0) {
        if (sub == 0) {
            const float* bp = bias + hd * C + cl * 4;
            float4 b = *(const float4*)bp;
            float r[4] = {acc.x + b.x, acc.y + b.y, acc.z + b.z, acc.w + b.w};
            ushort4 hv, lv;
            #pragma unroll
            for (int j = 0; j < 4; j++)
                r[j] = (r[j] > 0.f) ? r[j] : (expf(r[j]) - 1.f);   // ELU
            hv.x = f2bf(r[0]); lv.x = f2bf(r[0] - bf2f(hv.x));
            hv.y = f2bf(r[1]); lv.y = f2bf(r[1] - bf2f(hv.y));
            hv.z = f2bf(r[2]); lv.z = f2bf(r[2] - bf2f(hv.z));
            hv.w = f2bf(r[3]); lv.w = f2bf(r[3] - bf2f(hv.w));
            size_t base = (size_t)n * (HEADS * C) + hd * C + cl * 4;
            *(ushort4*)(oh + base) = hv;
            *(ushort4*)(ol + base) = lv;
        }
    } else {
        // C == 256, LPE == 64: every lane holds 4 channels of its head
        *(float4*)&red[hd * 256 + lane * 4] = acc;
        __syncthreads();
        int tid = threadIdx.x;
        if (tid < 256) {
            float s = 0.f;
            #pragma unroll
            for (int hh = 0; hh < HEADS; hh++) s += red[hh * 256 + tid];
            outf[(size_t)n * 256 + tid] = s * 0.125f + bias[tid];
        }
    }
}

// ---------------- launch ----------------
extern "C" void kernel_launch(void* const* d_in, const int* in_sizes, int n_in,
                              void* d_out, int out_size, void* d_ws, size_t ws_size,
                              hipStream_t stream) {
    const float* x   = (const float*)d_in[0];
    const int*   ei  = (const int*)d_in[1];
    const float* W1  = (const float*)d_in[2];
    const float* as1 = (const float*)d_in[3];
    const float* ad1 = (const float*)d_in[4];
    const float* b1  = (const float*)d_in[5];
    const float* W2  = (const float*)d_in[6];
    const float* as2 = (const float*)d_in[7];
    const float* ad2 = (const float*)d_in[8];
    const float* b2  = (const float*)d_in[9];
    const float* W3  = (const float*)d_in[10];
    const float* as3 = (const float*)d_in[11];
    const float* ad3 = (const float*)d_in[12];
    const float* b3  = (const float*)d_in[13];
    float* out = (float*)d_out;

    int* deg    = (int*)d_ws;
    int* cursor = deg + 10240;
    int* rows   = cursor + 10240;
    int* esrc   = rows + 10240;
    float* asrc = (float*)(esrc + 170240);
    float* adst = asrc + 81920;
    float* H    = adst + 81920;
    u16* Ahg    = (u16*)(H + (size_t)NNODES * 2048);
    u16* Alg    = Ahg + (size_t)NNODES * 1024;
    u16* Whg    = Alg + (size_t)NNODES * 1024;
    u16* Wlg    = Whg + (size_t)2048 * 1024;

    hipMemsetAsync(deg, 0, 2 * 10240 * sizeof(int), stream);

    count_k<<<(TOT_E + 255) / 256, 256, 0, stream>>>(ei, deg);
    scan_k<<<1, 1024, 0, stream>>>(deg, rows);
    scatter_k<<<(TOT_E + 255) / 256, 256, 0, stream>>>(ei, rows, cursor, esrc);

    const int rowBlocks = (NNODES + 127) / 128;

    // ---- layer 1: IN=256 -> 8x64 concat ----
    split4_k<<<(NNODES * 256 / 4 + 255) / 256, 256, 0, stream>>>(x, Ahg, Alg, NNODES * 256 / 4);
    split4_k<<<(512 * 256 / 4 + 255) / 256, 256, 0, stream>>>(W1, Whg, Wlg, 512 * 256 / 4);
    gemm_mfma<<<dim3(4, rowBlocks), 256, 0, stream>>>(Ahg, Alg, Whg, Wlg, H, NNODES, 512, 256);
    alphas_k<64><<<NNODES, 512, 0, stream>>>(H, as1, ad1, asrc, adst);
    agg_k<64, 0><<<NNODES, 512, 0, stream>>>(H, asrc, adst, rows, esrc, b1, Ahg, Alg, nullptr);

    // ---- layer 2: 512 -> 8x128 concat ----
    split4_k<<<(1024 * 512 / 4 + 255) / 256, 256, 0, stream>>>(W2, Whg, Wlg, 1024 * 512 / 4);
    gemm_mfma<<<dim3(8, rowBlocks), 256, 0, stream>>>(Ahg, Alg, Whg, Wlg, H, NNODES, 1024, 512);
    alphas_k<128><<<NNODES, 512, 0, stream>>>(H, as2, ad2, asrc, adst);
    agg_k<128, 0><<<NNODES, 512, 0, stream>>>(H, asrc, adst, rows, esrc, b2, Ahg, Alg, nullptr);

    // ---- layer 3: 1024 -> 8x256 mean ----
    split4_k<<<(2048 * 1024 / 4 + 255) / 256, 256, 0, stream>>>(W3, Whg, Wlg, 2048 * 1024 / 4);
    gemm_mfma<<<dim3(16, rowBlocks), 256, 0, stream>>>(Ahg, Alg, Whg, Wlg, H, NNODES, 2048, 1024);
    alphas_k<256><<<NNODES, 512, 0, stream>>>(H, as3, ad3, asrc, adst);
    agg_k<256, 1><<<NNODES, 512, 0, stream>>>(H, asrc, adst, rows, esrc, b3, nullptr, nullptr, out);
}